// Round 11
// baseline (396.043 us; speedup 1.0000x reference)
//
#include <hip/hip_runtime.h>
#include <hip/hip_bf16.h>

#define S_LEN 4096
#define HDIM  2048
#define NHQ   8
#define NKVH  2
#define DHEAD 256
#define WIN   512
#define NQKV  3072   // fused q+k+v projection width (2048 + 512 + 512)

typedef __hip_bfloat16 bf16_t;
using fragAB = __attribute__((ext_vector_type(8))) short;  // 8 bf16
using fragC  = __attribute__((ext_vector_type(4))) float;  // 4 fp32

struct __align__(8)  bf16x4 { bf16_t v[4]; };
struct __align__(16) bf16x8 { bf16_t v[8]; };

typedef unsigned int u32;
typedef const __attribute__((address_space(1))) u32* gas_ptr;
typedef __attribute__((address_space(3))) u32* las_ptr;

__device__ __forceinline__ void async_copy16(const void* g, void* l) {
  __builtin_amdgcn_global_load_lds((gas_ptr)g, (las_ptr)l, 16, 0, 0);
}

#define NEG_BIG (-3.0e38f)

__device__ __forceinline__ void split2(float x, bf16_t& hi, bf16_t& lo) {
  bf16_t h = __float2bfloat16(x);
  hi = h;
  lo = __float2bfloat16(x - (float)h);
}

// ---------------------------------------------------------------------------
// prep0: fused phase-0 prep (one dispatch).
//  blockIdx.x <  4096 : split hidden fp32 -> bf16 hi/lo (8 elem/thread, 16B st)
//  blockIdx.x >= 4096 : transpose+split [wq|wk|wv] -> wT hi/lo [3072][2048]
// ---------------------------------------------------------------------------
__global__ __launch_bounds__(256) void prep0(
    const float* __restrict__ hid, bf16_t* __restrict__ hidh,
    bf16_t* __restrict__ hidl, const float* __restrict__ wq,
    const float* __restrict__ wk, const float* __restrict__ wv,
    bf16_t* __restrict__ hiT, bf16_t* __restrict__ loT) {
  __shared__ bf16_t th[32][33];
  __shared__ bf16_t tl[32][33];
  int bx = blockIdx.x;
  if (bx < 4096) {
    int i = (bx * 256 + threadIdx.x) * 8;
    float4 a = *(const float4*)(hid + i);
    float4 b = *(const float4*)(hid + i + 4);
    float xs[8] = {a.x, a.y, a.z, a.w, b.x, b.y, b.z, b.w};
    bf16x8 hv, lv;
#pragma unroll
    for (int j = 0; j < 8; ++j) split2(xs[j], hv.v[j], lv.v[j]);
    *(bf16x8*)(hidh + i) = hv;
    *(bf16x8*)(hidl + i) = lv;
  } else {
    int b2 = bx - 4096;
    int oc = (b2 % 96) * 32;   // output row group (input col)
    int r0 = (b2 / 96) * 32;   // input row
    const float* src; int C, c0;
    if (oc < 2048)      { src = wq; C = 2048; c0 = oc; }
    else if (oc < 2560) { src = wk; C = 512;  c0 = oc - 2048; }
    else                { src = wv; C = 512;  c0 = oc - 2560; }
    int tx = threadIdx.x & 31, ty = threadIdx.x >> 5;
#pragma unroll
    for (int i = 0; i < 4; ++i) {
      float x = src[(size_t)(r0 + ty + i * 8) * C + c0 + tx];
      bf16_t h, l; split2(x, h, l);
      th[ty + i * 8][tx] = h;
      tl[ty + i * 8][tx] = l;
    }
    __syncthreads();
#pragma unroll
    for (int i = 0; i < 4; ++i) {
      hiT[(size_t)(oc + ty + i * 8) * HDIM + r0 + tx] = th[tx][ty + i * 8];
      loT[(size_t)(oc + ty + i * 8) * HDIM + r0 + tx] = tl[tx][ty + i * 8];
    }
  }
}

// ---------------------------------------------------------------------------
// Shared helpers for pipelined GEMMs
// ---------------------------------------------------------------------------
#define VMCNT_(n) asm volatile("s_waitcnt vmcnt(" #n ")" ::: "memory")
#define VMCNT(n) VMCNT_(n)
#define BARRIER()                     \
  {                                   \
    asm volatile("" ::: "memory");    \
    __builtin_amdgcn_s_barrier();     \
    asm volatile("" ::: "memory");    \
  }

#define MFMA_(a, b, c) __builtin_amdgcn_mfma_f32_16x16x32_bf16(a, b, c, 0, 0, 0)

// ---------------------------------------------------------------------------
// Split-precision GEMM v6: C = Ah*Bh + Ah*Bl + Al*Bh, pipelined.
// BM=256, BN=192, BK=32, 1024 threads (16 waves = 4 waves/SIMD), wave tile
// 64x48 (4M x 4N, acc 4x3). Staging: 56 chunks = 3/wave + 4th on waves 0-7.
// Double-buffered LDS (112 KB), ONE barrier + one vmcnt(0) per K-step —
// sync structure, swizzles, and per-element MFMA k-order IDENTICAL to the
// verified 12-wave v5 (bitwise-identical output). XCD-chunked swizzle.
// ---------------------------------------------------------------------------
#define OFF_AH 0
#define OFF_AL 16384
#define OFF_BH 32768
#define OFF_BL 45056
#define BUFSZ  57344

#define SPLIT_STEP()                                                    \
  {                                                                     \
    fragAB bh[3], bl[3];                                                \
    _Pragma("unroll") for (int j = 0; j < 3; ++j) {                     \
      const char* bp = bufc + (wn + j * 16 + l16) * 64 + rdq;           \
      bh[j] = *(const fragAB*)(bp + OFF_BH);                            \
      bl[j] = *(const fragAB*)(bp + OFF_BL);                            \
    }                                                                   \
    _Pragma("unroll") for (int p = 0; p < 2; ++p) {                     \
      fragAB ah[2], al[2];                                              \
      _Pragma("unroll") for (int u = 0; u < 2; ++u) {                   \
        const char* ap = bufc + (wm + (2 * p + u) * 16 + l16) * 64 + rdq;\
        ah[u] = *(const fragAB*)(ap + OFF_AH);                          \
        al[u] = *(const fragAB*)(ap + OFF_AL);                          \
      }                                                                 \
      __builtin_amdgcn_s_setprio(1);                                    \
      _Pragma("unroll") for (int j = 0; j < 3; ++j)                     \
        _Pragma("unroll") for (int u = 0; u < 2; ++u)                   \
          acc[2 * p + u][j] = MFMA_(al[u], bh[j], acc[2 * p + u][j]);   \
      _Pragma("unroll") for (int j = 0; j < 3; ++j)                     \
        _Pragma("unroll") for (int u = 0; u < 2; ++u)                   \
          acc[2 * p + u][j] = MFMA_(ah[u], bl[j], acc[2 * p + u][j]);   \
      _Pragma("unroll") for (int j = 0; j < 3; ++j)                     \
        _Pragma("unroll") for (int u = 0; u < 2; ++u)                   \
          acc[2 * p + u][j] = MFMA_(ah[u], bh[j], acc[2 * p + u][j]);   \
      __builtin_amdgcn_s_setprio(0);                                    \
    }                                                                   \
  }

__global__ __launch_bounds__(1024, 4) void gemm_split2(
    const bf16_t* __restrict__ Ah, const bf16_t* __restrict__ Al,
    const bf16_t* __restrict__ Bh, const bf16_t* __restrict__ Bl,
    float* __restrict__ C, int M, int N, int K) {
  __shared__ __align__(16) char lds[2 * BUFSZ];
  const int t = threadIdx.x;
  const int wave = t >> 6, lane = t & 63;
  const int quad = lane >> 4, l16 = lane & 15;
  // XCD-chunked swizzle (grid 16x16 = 256 = 32/XCD): bijective relabel.
  const int g = blockIdx.y * 16 + blockIdx.x;
  const int lby = (g & 7) * 2 + ((g >> 3) >> 4);
  const int lbx = (g >> 3) & 15;
  const int m0 = lby * 256, n0 = lbx * 192;
  const int wm = (wave >> 2) * 64, wn = (wave & 3) * 48;
  // T2 read swizzle: phys 16B-slot of (row r, col-16B q) = q ^ ((r>>1)&3).
  const int rdq = (quad ^ ((l16 >> 1) & 3)) * 16;

  // Per-lane global source offset inside a 16-row x 32-col chunk (inverse swizzle).
  const size_t laneOff =
      (size_t)(lane >> 2) * K * 2 + 16 * ((lane & 3) ^ ((lane >> 3) & 3));

  // 56 staging chunks: wave w takes c = w+16*pos (pos<3); waves 0-7 also c=48+w.
  //  c<12: Bh ; c<24: Bl ; c<40: Ah ; c<56: Al   (16-row x 1024B chunks)
  const char* gbase[4];
  int ldsOff[4];
  const int nch = (wave < 8) ? 4 : 3;
#pragma unroll
  for (int pos = 0; pos < 4; ++pos) {
    int c = (pos < 3) ? (wave + 16 * pos) : (48 + wave);
    const char* gb; int lo;
    if (c < 12)      { gb = (const char*)Bh + (size_t)(n0 + 16 * c) * K * 2;        lo = OFF_BH + c * 1024; }
    else if (c < 24) { gb = (const char*)Bl + (size_t)(n0 + 16 * (c - 12)) * K * 2; lo = OFF_BL + (c - 12) * 1024; }
    else if (c < 40) { gb = (const char*)Ah + (size_t)(m0 + 16 * (c - 24)) * K * 2; lo = OFF_AH + (c - 24) * 1024; }
    else             { gb = (const char*)Al + (size_t)(m0 + 16 * (c - 40)) * K * 2; lo = OFF_AL + (c - 40) * 1024; }
    gbase[pos] = gb;
    ldsOff[pos] = lo;
  }

  fragC zero4 = {0.f, 0.f, 0.f, 0.f};
  fragC acc[4][3];
#pragma unroll
  for (int i = 0; i < 4; ++i)
#pragma unroll
    for (int j = 0; j < 3; ++j) acc[i][j] = zero4;

  char* ldsc = (char*)lds;
  // prologue: stage K-step 0 into buffer 0
  for (int ps = 0; ps < nch; ++ps)
    async_copy16(gbase[ps] + laneOff, ldsc + ldsOff[ps]);

  size_t kk = 64;  // byte offset of next K-step (32 bf16 = 64 B)
  int cur = 0;
  const int NS = K / 32;
  for (int it = 0; it < NS - 1; ++it) {
    const char* bufc = ldsc + cur * BUFSZ;
    char* nb = ldsc + (cur ^ 1) * BUFSZ;
    // drain own loads (issued a full K-step ago -> free) and rendezvous;
    // after the barrier, nb is safe to overwrite.
    VMCNT(0); BARRIER();
    for (int ps = 0; ps < nch; ++ps)
      async_copy16(gbase[ps] + kk + laneOff, nb + ldsOff[ps]);
    kk += 64;
    SPLIT_STEP();
    cur ^= 1;
  }
  {  // final K-step
    const char* bufc = ldsc + cur * BUFSZ;
    VMCNT(0); BARRIER();
    SPLIT_STEP();
  }

#pragma unroll
  for (int i = 0; i < 4; ++i)
#pragma unroll
    for (int j = 0; j < 3; ++j)
#pragma unroll
      for (int r = 0; r < 4; ++r) {
        int row = m0 + wm + i * 16 + quad * 4 + r;
        int col = n0 + wn + j * 16 + l16;
        C[(size_t)row * N + col] = acc[i][j][r];
      }
}

// ---------------------------------------------------------------------------
// Plain GEMM v4 (output projection): C[M][N] = A[M][K]*Bt[N][K]^T, fp32 out.
// BM=256, BN=128, BK=64, 1024 threads (16 waves = 4 waves/SIMD), wave tile
// 64x32 (4M x 4N, acc 4x2). Staging: 48 chunks = 3/wave. Same 1-barrier +
// vmcnt(0) per K-step schedule; per-element MFMA k-order unchanged
// (bitwise-identical to the verified 8-wave v3). XCD-chunked swizzle.
// ---------------------------------------------------------------------------
#define BT_OFF_A 0
#define BT_OFF_B 32768
#define BT_BUFSZ 49152

#define BT_STEP()                                                         \
  {                                                                       \
    fragAB bfr[2][2];                                                     \
    _Pragma("unroll") for (int j = 0; j < 2; ++j)                         \
      _Pragma("unroll") for (int ks = 0; ks < 2; ++ks)                    \
        bfr[j][ks] = *(const fragAB*)(bufc + BT_OFF_B +                   \
                                      (wn + j * 16 + l16) * 128 +         \
                                      (((ks * 4 + quad) ^ rx) * 16));     \
    _Pragma("unroll") for (int p = 0; p < 2; ++p) {                       \
      fragAB af[2][2];                                                    \
      _Pragma("unroll") for (int u = 0; u < 2; ++u)                       \
        _Pragma("unroll") for (int ks = 0; ks < 2; ++ks)                  \
          af[u][ks] = *(const fragAB*)(bufc + BT_OFF_A +                  \
                                       (wm + (2 * p + u) * 16 + l16) * 128 + \
                                       (((ks * 4 + quad) ^ rx) * 16));    \
      __builtin_amdgcn_s_setprio(1);                                      \
      _Pragma("unroll") for (int ks = 0; ks < 2; ++ks)                    \
        _Pragma("unroll") for (int j = 0; j < 2; ++j)                     \
          _Pragma("unroll") for (int u = 0; u < 2; ++u)                   \
            acc[2 * p + u][j] = MFMA_(af[u][ks], bfr[j][ks], acc[2 * p + u][j]); \
      __builtin_amdgcn_s_setprio(0);                                      \
    }                                                                     \
  }

__global__ __launch_bounds__(1024, 4) void gemm_bt2(
    const bf16_t* __restrict__ A, const bf16_t* __restrict__ Bt,
    float* __restrict__ C, int M, int N, int K) {
  __shared__ __align__(16) char lds[2 * BT_BUFSZ];
  const int t = threadIdx.x;
  const int wave = t >> 6, lane = t & 63;
  const int quad = lane >> 4, l16 = lane & 15;
  const int g = blockIdx.y * 16 + blockIdx.x;
  const int lby = (g & 7) * 2 + ((g >> 3) >> 4);
  const int lbx = (g >> 3) & 15;
  const int m0 = lby * 256, n0 = lbx * 128;
  const int wm = (wave >> 2) * 64, wn = (wave & 3) * 32;
  const int rx = l16 & 7;  // row-XOR for 8-slot swizzle (128B rows)

  // chunk = 8 rows x 64 cols (128B rows). lane l stages row l>>3,
  // logical col16 (l&7)^((l>>3)&7) -> LDS phys slot l&7 (inverse swizzle).
  const size_t laneOff =
      (size_t)(lane >> 3) * K * 2 + 16 * ((lane & 7) ^ ((lane >> 3) & 7));

  // 48 staging chunks: wave w takes c = w+16*pos (pos<3).
  //  c<16: B chunk c (rows 8c) ; c>=16: A chunk c-16 (rows 8(c-16))
  const char* gbase[3];
  int ldsOff[3];
#pragma unroll
  for (int pos = 0; pos < 3; ++pos) {
    int c = wave + 16 * pos;
    if (c < 16) {
      gbase[pos]  = (const char*)Bt + (size_t)(n0 + 8 * c) * K * 2;
      ldsOff[pos] = BT_OFF_B + c * 1024;
    } else {
      gbase[pos]  = (const char*)A + (size_t)(m0 + 8 * (c - 16)) * K * 2;
      ldsOff[pos] = BT_OFF_A + (c - 16) * 1024;
    }
  }

  fragC zero4 = {0.f, 0.f, 0.f, 0.f};
  fragC acc[4][2];
#pragma unroll
  for (int i = 0; i < 4; ++i)
#pragma unroll
    for (int j = 0; j < 2; ++j) acc[i][j] = zero4;

  char* ldsc = (char*)lds;
#pragma unroll
  for (int ps = 0; ps < 3; ++ps)
    async_copy16(gbase[ps] + laneOff, ldsc + ldsOff[ps]);

  size_t kk = 128;  // byte offset of next K-step (64 bf16 = 128 B)
  int cur = 0;
  const int NS = K / 64;
  for (int it = 0; it < NS - 1; ++it) {
    const char* bufc = ldsc + cur * BT_BUFSZ;
    char* nb = ldsc + (cur ^ 1) * BT_BUFSZ;
    VMCNT(0); BARRIER();
#pragma unroll
    for (int ps = 0; ps < 3; ++ps)
      async_copy16(gbase[ps] + kk + laneOff, nb + ldsOff[ps]);
    kk += 128;
    BT_STEP();
    cur ^= 1;
  }
  {
    const char* bufc = ldsc + cur * BT_BUFSZ;
    VMCNT(0); BARRIER();
    BT_STEP();
  }

#pragma unroll
  for (int i = 0; i < 4; ++i)
#pragma unroll
    for (int j = 0; j < 2; ++j)
#pragma unroll
      for (int r = 0; r < 4; ++r) {
        int row = m0 + wm + i * 16 + quad * 4 + r;
        int col = n0 + wn + j * 16 + l16;
        C[(size_t)row * N + col] = acc[i][j][r];
      }
}

// ---------------------------------------------------------------------------
// prep2: fused phase-2 norms + w_o transpose (one dispatch).
//  bx <  10240         : RMS-norm+RoPE q/k, wave-per-(s,head), split output
//  10240 <= bx < 10496 : RMS-norm v + transposed write [NKV][D][S]
//  bx >= 10496         : transpose+convert w_o -> woT  (woT ALIASES wTl;
//                        this kernel runs AFTER gemm_split2 -- lifetime OK)
// ---------------------------------------------------------------------------
__global__ __launch_bounds__(256) void prep2(
    const float* __restrict__ proj, const float* __restrict__ qnw,
    const float* __restrict__ knw, const float* __restrict__ cosb,
    const float* __restrict__ sinb, bf16_t* __restrict__ qhi,
    bf16_t* __restrict__ qlo, bf16_t* __restrict__ khi,
    bf16_t* __restrict__ klo, bf16_t* __restrict__ vt,
    const float* __restrict__ wo, bf16_t* __restrict__ woT) {
  __shared__ float rs_[32];
  __shared__ bf16_t tile[32][33];
  int bx = blockIdx.x;
  if (bx < 10240) {
    // ---- RMS-norm + RoPE for q/k heads (wave-per-(s,head)) ----
    const int wv = threadIdx.x >> 6, lane = threadIdx.x & 63;
    const int idx = bx * 4 + wv;
    const int s = idx / (NHQ + NKVH), hb = idx % (NHQ + NKVH);
    const float* w; bf16_t* oh; bf16_t* ol; int inOff, outStride, oBase;
    if (hb < NHQ) {
      w = qnw; oh = qhi; ol = qlo;
      inOff = hb * DHEAD; outStride = NHQ * DHEAD; oBase = hb * DHEAD;
    } else {
      int hk = hb - NHQ;
      w = knw; oh = khi; ol = klo;
      inOff = NHQ * DHEAD + hk * DHEAD; outStride = NKVH * DHEAD; oBase = hk * DHEAD;
    }
    const int d = lane * 4;
    float4 x = *(const float4*)(proj + (size_t)s * NQKV + inOff + d);
    float ss = x.x * x.x + x.y * x.y + x.z * x.z + x.w * x.w;
    ss += __shfl_xor(ss, 1);  ss += __shfl_xor(ss, 2);  ss += __shfl_xor(ss, 4);
    ss += __shfl_xor(ss, 8);  ss += __shfl_xor(ss, 16); ss += __shfl_xor(ss, 32);
    float r = rsqrtf(ss * (1.0f / DHEAD) + 1e-6f);
    float4 w4 = *(const float4*)(w + d);
    float xn[4] = {x.x * r * w4.x, x.y * r * w4.y, x.z * r * w4.z, x.w * r * w4.w};
    float ot[4];
#pragma unroll
    for (int j = 0; j < 4; ++j) ot[j] = __shfl_xor(xn[j], 32);
    float sgn = (lane < 32) ? -1.0f : 1.0f;
    float4 c4 = *(const float4*)(cosb + (size_t)s * DHEAD + d);
    float4 s4 = *(const float4*)(sinb + (size_t)s * DHEAD + d);
    float cc[4] = {c4.x, c4.y, c4.z, c4.w};
    float sn[4] = {s4.x, s4.y, s4.z, s4.w};
    bf16x4 hv, lv;
#pragma unroll
    for (int j = 0; j < 4; ++j) {
      float y = xn[j] * cc[j] + sgn * ot[j] * sn[j];
      split2(y, hv.v[j], lv.v[j]);
    }
    size_t o = (size_t)s * outStride + oBase + d;
    *(bf16x4*)(oh + o) = hv;
    *(bf16x4*)(ol + o) = lv;
  } else if (bx < 10240 + 256) {
    // ---- RMS-norm v (no weight) + transposed write [NKV][D][S] ----
    int b2 = bx - 10240;
    int s0 = (b2 & 127) * 32, hh = b2 >> 7;
    const int inOff = NHQ * DHEAD + NKVH * DHEAD;
    const float* base = proj + (size_t)s0 * NQKV + inOff + hh * DHEAD;
    int t = threadIdx.x;
    int sl = t >> 3, c8 = t & 7;
    const float4* rowp = (const float4*)(base + (size_t)sl * NQKV + c8 * 32);
    float ss = 0.f;
#pragma unroll
    for (int i = 0; i < 8; ++i) {
      float4 v = rowp[i];
      ss += v.x * v.x + v.y * v.y + v.z * v.z + v.w * v.w;
    }
    ss += __shfl_xor(ss, 1); ss += __shfl_xor(ss, 2); ss += __shfl_xor(ss, 4);
    if (c8 == 0) rs_[sl] = rsqrtf(ss * (1.0f / DHEAD) + 1e-6f);
    __syncthreads();
    int tx = t & 31, ty = t >> 5;
#pragma unroll
    for (int ch = 0; ch < 8; ++ch) {
#pragma unroll
      for (int i = 0; i < 4; ++i) {
        int s_ = ty + i * 8;
        float x = base[(size_t)s_ * NQKV + ch * 32 + tx];
        tile[s_][tx] = __float2bfloat16(x * rs_[s_]);
      }
      __syncthreads();
#pragma unroll
      for (int i = 0; i < 4; ++i) {
        int dl = ty + i * 8;
        vt[((size_t)hh * DHEAD + ch * 32 + dl) * S_LEN + s0 + tx] = tile[tx][dl];
      }
      __syncthreads();
    }
  } else {
    // ---- transpose+convert w_o [2048][2048] -> woT ----
    int b2 = bx - 10496;
    int c0 = (b2 & 63) * 32, r0 = (b2 >> 6) * 32;
    int tx = threadIdx.x & 31, ty = threadIdx.x >> 5;
#pragma unroll
    for (int i = 0; i < 4; ++i)
      tile[ty + i * 8][tx] =
          __float2bfloat16(wo[(size_t)(r0 + ty + i * 8) * HDIM + c0 + tx]);
    __syncthreads();
#pragma unroll
    for (int i = 0; i < 4; ++i)
      woT[(size_t)(c0 + ty + i * 8) * (NHQ * DHEAD) + r0 + tx] = tile[tx][ty + i * 8];
  }
}

// ---------------------------------------------------------------------------
// Flash attention v4: Q=128, KV=32, dbuf, 1 barrier/step, setprio around
// MFMA clusters, XCD-chunked block swizzle.
// ---------------------------------------------------------------------------
__global__ __launch_bounds__(512, 2) void attn_split(
    const bf16_t* __restrict__ Qhi, const bf16_t* __restrict__ Qlo,
    const bf16_t* __restrict__ Khi, const bf16_t* __restrict__ Klo,
    const bf16_t* __restrict__ Vt, bf16_t* __restrict__ Aout) {
  const int g = blockIdx.y * 32 + blockIdx.x;
  const int lbx = (g & 7) * 4 + ((g >> 3) & 3);
  const int h = g >> 5;
  const int qb = lbx * 128;
  const int wave = threadIdx.x >> 6, lane = threadIdx.x & 63;
  const int quad = lane >> 4, l16 = lane & 15;
  const int qw = qb + wave * 16;
  const int kv = h >> 2;  // G = 4
  const bf16_t* Qh_ = Qhi + h * DHEAD;   // row stride NHQ*DHEAD
  const bf16_t* Ql_ = Qlo + h * DHEAD;
  const bf16_t* Kh_ = Khi + kv * DHEAD;  // row stride NKVH*DHEAD
  const bf16_t* Kl_ = Klo + kv * DHEAD;
  const bf16_t* Vh_ = Vt + (size_t)kv * DHEAD * S_LEN;

  __shared__ __align__(16) bf16_t KshH[2][32 * 256];  // 2x16 KB (keys x d)
  __shared__ __align__(16) bf16_t KshL[2][32 * 256];  // 2x16 KB
  __shared__ __align__(16) bf16_t Vsh[2][256 * 32];   // 2x16 KB (d x keys)
  __shared__ __align__(16) bf16_t Plds[8][16 * 32];   // 8 KB

  fragAB qfh[8], qfl[8];
#pragma unroll
  for (int c = 0; c < 8; ++c) {
    size_t off = (size_t)(qw + l16) * (NHQ * DHEAD) + c * 32 + quad * 8;
    qfh[c] = *(const fragAB*)(Qh_ + off);
    qfl[c] = *(const fragAB*)(Ql_ + off);
  }

  int kRow[2], kCol[2], vRow[2], vCol[2];
#pragma unroll
  for (int i = 0; i < 2; ++i) {
    int ci = i * 512 + threadIdx.x;
    kRow[i] = ci >> 5;
    kCol[i] = ((ci & 31) ^ (kRow[i] & 31)) * 8;
    vRow[i] = ci >> 2;
    vCol[i] = ((ci & 3) ^ (vRow[i] & 3)) * 8;
  }

#define ASTAGE(buf, kb_)                                                     \
  _Pragma("unroll")                                                          \
  for (int i = 0; i < 2; ++i) {                                              \
    size_t dst = (size_t)(i * 512 + threadIdx.x) * 16;                       \
    size_t koff = (size_t)((kb_) + kRow[i]) * (NKVH * DHEAD) + kCol[i];      \
    async_copy16(Kh_ + koff, (char*)KshH[buf] + dst);                        \
    async_copy16(Kl_ + koff, (char*)KshL[buf] + dst);                        \
    async_copy16(Vh_ + (size_t)vRow[i] * S_LEN + (kb_) + vCol[i],            \
                 (char*)Vsh[buf] + dst);                                     \
  }

  fragC zero4 = {0.f, 0.f, 0.f, 0.f};
  fragC o_acc[16];
#pragma unroll
  for (int c = 0; c < 16; ++c) o_acc[c] = zero4;
  float m_run[4] = {NEG_BIG, NEG_BIG, NEG_BIG, NEG_BIG};
  float l_run[4] = {0.f, 0.f, 0.f, 0.f};
  const float LOG2E = 1.4426950408889634f;

  int k_lo = qb - (WIN - 1);
  if (k_lo < 0) k_lo = 0;
  k_lo &= ~31;

  // prologue: stage first KV tile into buffer 0
  ASTAGE(0, k_lo);
  int cur = 0;

  for (int kb = k_lo; kb < qb + 128; kb += 32) {
    VMCNT(0); BARRIER();
    if (kb + 32 < qb + 128) {
      int nbuf = cur ^ 1;
      ASTAGE(nbuf, kb + 32);
    }
    const char* KH = (const char*)KshH[cur];
    const char* KL = (const char*)KshL[cur];
    const char* VB = (const char*)Vsh[cur];

    fragC s[2] = {zero4, zero4};
    __builtin_amdgcn_s_setprio(1);
#pragma unroll
    for (int c = 0; c < 8; ++c) {
      int j = c * 4 + quad;
#pragma unroll
      for (int gg = 0; gg < 2; ++gg) {
        int row = gg * 16 + l16;
        int off = (row * 32 + (j ^ (row & 31))) * 16;
        fragAB kh = *(const fragAB*)(KH + off);
        fragAB kl = *(const fragAB*)(KL + off);
        s[gg] = __builtin_amdgcn_mfma_f32_16x16x32_bf16(qfl[c], kh, s[gg], 0, 0, 0);
        s[gg] = __builtin_amdgcn_mfma_f32_16x16x32_bf16(qfh[c], kl, s[gg], 0, 0, 0);
        s[gg] = __builtin_amdgcn_mfma_f32_16x16x32_bf16(qfh[c], kh, s[gg], 0, 0, 0);
      }
    }
    __builtin_amdgcn_s_setprio(0);

    float p[2][4], alpha[4];
#pragma unroll
    for (int r = 0; r < 4; ++r) {
      int qi = qw + quad * 4 + r;
      bool vld[2];
      float mx = NEG_BIG;
#pragma unroll
      for (int gg = 0; gg < 2; ++gg) {
        int ki = kb + gg * 16 + l16;
        vld[gg] = (ki <= qi) && (qi - ki < WIN);
        mx = fmaxf(mx, vld[gg] ? s[gg][r] : NEG_BIG);
      }
      mx = fmaxf(mx, __shfl_xor(mx, 1));
      mx = fmaxf(mx, __shfl_xor(mx, 2));
      mx = fmaxf(mx, __shfl_xor(mx, 4));
      mx = fmaxf(mx, __shfl_xor(mx, 8));
      float mn = fmaxf(m_run[r], mx);
      float a  = exp2f(fmaxf(m_run[r] - mn, -80.f) * LOG2E);
      float rs = 0.f;
#pragma unroll
      for (int gg = 0; gg < 2; ++gg) {
        float e = vld[gg] ? exp2f(fmaxf(s[gg][r] - mn, -80.f) * LOG2E) : 0.f;
        p[gg][r] = e;
        rs += e;
      }
      rs += __shfl_xor(rs, 1);
      rs += __shfl_xor(rs, 2);
      rs += __shfl_xor(rs, 4);
      rs += __shfl_xor(rs, 8);
      l_run[r] = l_run[r] * a + rs;
      m_run[r] = mn;
      alpha[r] = a;
    }
#pragma unroll
    for (int c = 0; c < 16; ++c)
#pragma unroll
      for (int r = 0; r < 4; ++r) o_acc[c][r] *= alpha[r];

    bf16_t* Pw = Plds[wave];
#pragma unroll
    for (int r = 0; r < 4; ++r)
#pragma unroll
      for (int gg = 0; gg < 2; ++gg)
        Pw[(quad * 4 + r) * 32 + gg * 16 + l16] = __float2bfloat16(p[gg][r]);
    fragAB pf = *(const fragAB*)((const char*)Pw + l16 * 64 + quad * 16);

    __builtin_amdgcn_s_setprio(1);
#pragma unroll
    for (int c = 0; c < 16; ++c) {
      int d = c * 16 + l16;
      int offv = (d * 4 + (quad ^ (d & 3))) * 16;
      fragAB vf = *(const fragAB*)(VB + offv);
      o_acc[c] = __builtin_amdgcn_mfma_f32_16x16x32_bf16(pf, vf, o_acc[c], 0, 0, 0);
    }
    __builtin_amdgcn_s_setprio(0);
    cur ^= 1;
  }

  float inv_l[4];
#pragma unroll
  for (int r = 0; r < 4; ++r) inv_l[r] = 1.0f / l_run[r];
#pragma unroll
  for (int c = 0; c < 16; ++c)
#pragma unroll
    for (int r = 0; r < 4; ++r) {
      int row = qw + quad * 4 + r;
      int col = h * DHEAD + c * 16 + l16;
      Aout[(size_t)row * (NHQ * DHEAD) + col] = __float2bfloat16(o_acc[c][r] * inv_l[r]);
    }
#undef ASTAGE
}

// ---------------------------------------------------------------------------
extern "C" void kernel_launch(void* const* d_in, const int* in_sizes, int n_in,
                              void* d_out, int out_size, void* d_ws, size_t ws_size,
                              hipStream_t stream) {
  const float* hid  = (const float*)d_in[0];
  const float* w_q  = (const float*)d_in[1];
  const float* w_k  = (const float*)d_in[2];
  const float* w_v  = (const float*)d_in[3];
  const float* w_o  = (const float*)d_in[4];
  const float* qnw  = (const float*)d_in[5];
  const float* knw  = (const float*)d_in[6];
  const float* cosb = (const float*)d_in[7];
  const float* sinb = (const float*)d_in[8];
  float* outp = (float*)d_out;

  // Workspace (bf16 slots, M1 = 1<<20), peak 52M slots = 104 MiB:
  //  [ 0: 8M)  hidh  -> qh  (after qkv gemm)
  //  [ 8:16M)  hidl  -> ql
  //  [16:22M)  wTh (3072x2048) -> kh[16:18M), kl[18:20M), vt[20:22M) after gemm
  //  [22:28M)  wTl   -> woT[22:26M) after gemm  (LIFETIME: woT writes must
  //            come AFTER gemm_split2 — rounds 6/7 bug wrote it at phase 0)
  //  [28:52M)  projqkv f32 (4096x3072) -> aout[28:36M) after norms
  const size_t M1 = 1048576;
  bf16_t* w = (bf16_t*)d_ws;
  bf16_t* hidh  = w;
  bf16_t* qh    = w;                         // alias hidh
  bf16_t* hidl  = w + 8 * M1;
  bf16_t* ql    = w + 8 * M1;                // alias hidl
  bf16_t* wTh   = w + 16 * M1;
  bf16_t* kh    = w + 16 * M1;               // alias wTh
  bf16_t* kl    = w + 18 * M1;
  bf16_t* vt    = w + 20 * M1;
  bf16_t* wTl   = w + 22 * M1;
  bf16_t* woT   = w + 22 * M1;               // alias wTl
  float*  projqkv = (float*)(w + 28 * M1);
  bf16_t* aout  = w + 28 * M1;               // alias projqkv (after norms)

  // phase 0: ONE dispatch — split hidden + split-transpose [wq|wk|wv]
  prep0<<<4096 + 96 * 64, 256, 0, stream>>>(
      hid, hidh, hidl, w_q, w_k, w_v, wTh, wTl);

  // phase 1: fused q+k+v split projection, pipelined 256x192 tiles
  //          grid 16x16 = 256 blocks = exactly 1 per CU, 16 waves (4/SIMD)
  gemm_split2<<<dim3(NQKV / 192, S_LEN / 256), 1024, 0, stream>>>(
      hidh, hidl, wTh, wTl, projqkv, S_LEN, NQKV, HDIM);

  // phase 2: ONE dispatch — q/k norm+rope, v norm+transpose, w_o transpose
  //          (woT aliases wTl: safe only AFTER gemm_split2)
  prep2<<<10240 + 256 + 4096, 256, 0, stream>>>(
      projqkv, qnw, knw, cosb, sinb, qh, ql, kh, kl, vt, w_o, woT);

  // phase 3: attention -> aout (dead projqkv region)
  //          grid 32x8 = 256 blocks = exactly 1 per CU
  attn_split<<<dim3(S_LEN / 128, NHQ), 512, 0, stream>>>(qh, ql, kh, kl, vt, aout);

  // phase 4: output projection -> fp32 d_out, pipelined 256x128 tiles
  //          grid 16x16 = 256 blocks = 1 per CU, 16 waves (4/SIMD)
  gemm_bt2<<<dim3(HDIM / 128, S_LEN / 256), 1024, 0, stream>>>(
      aout, woT, outp, S_LEN, HDIM, NHQ * DHEAD);
}

// Round 12
// 390.514 us; speedup vs baseline: 1.0142x; 1.0142x over previous
//
#include <hip/hip_runtime.h>
#include <hip/hip_bf16.h>

#define S_LEN 4096
#define HDIM  2048
#define NHQ   8
#define NKVH  2
#define DHEAD 256
#define WIN   512
#define NQKV  3072   // fused q+k+v projection width (2048 + 512 + 512)

typedef __hip_bfloat16 bf16_t;
using fragAB = __attribute__((ext_vector_type(8))) short;  // 8 bf16
using fragC  = __attribute__((ext_vector_type(4))) float;  // 4 fp32

struct __align__(8)  bf16x4 { bf16_t v[4]; };
struct __align__(16) bf16x8 { bf16_t v[8]; };

typedef unsigned int u32;
typedef const __attribute__((address_space(1))) u32* gas_ptr;
typedef __attribute__((address_space(3))) u32* las_ptr;

__device__ __forceinline__ void async_copy16(const void* g, void* l) {
  __builtin_amdgcn_global_load_lds((gas_ptr)g, (las_ptr)l, 16, 0, 0);
}

#define NEG_BIG (-3.0e38f)

__device__ __forceinline__ void split2(float x, bf16_t& hi, bf16_t& lo) {
  bf16_t h = __float2bfloat16(x);
  hi = h;
  lo = __float2bfloat16(x - (float)h);
}

// ---------------------------------------------------------------------------
// prep0: fused phase-0 prep (one dispatch).
//  blockIdx.x <  4096 : split hidden fp32 -> bf16 hi/lo (8 elem/thread, 16B st)
//  blockIdx.x >= 4096 : transpose+split [wq|wk|wv] -> wT hi/lo [3072][2048]
// ---------------------------------------------------------------------------
__global__ __launch_bounds__(256) void prep0(
    const float* __restrict__ hid, bf16_t* __restrict__ hidh,
    bf16_t* __restrict__ hidl, const float* __restrict__ wq,
    const float* __restrict__ wk, const float* __restrict__ wv,
    bf16_t* __restrict__ hiT, bf16_t* __restrict__ loT) {
  __shared__ bf16_t th[32][33];
  __shared__ bf16_t tl[32][33];
  int bx = blockIdx.x;
  if (bx < 4096) {
    int i = (bx * 256 + threadIdx.x) * 8;
    float4 a = *(const float4*)(hid + i);
    float4 b = *(const float4*)(hid + i + 4);
    float xs[8] = {a.x, a.y, a.z, a.w, b.x, b.y, b.z, b.w};
    bf16x8 hv, lv;
#pragma unroll
    for (int j = 0; j < 8; ++j) split2(xs[j], hv.v[j], lv.v[j]);
    *(bf16x8*)(hidh + i) = hv;
    *(bf16x8*)(hidl + i) = lv;
  } else {
    int b2 = bx - 4096;
    int oc = (b2 % 96) * 32;   // output row group (input col)
    int r0 = (b2 / 96) * 32;   // input row
    const float* src; int C, c0;
    if (oc < 2048)      { src = wq; C = 2048; c0 = oc; }
    else if (oc < 2560) { src = wk; C = 512;  c0 = oc - 2048; }
    else                { src = wv; C = 512;  c0 = oc - 2560; }
    int tx = threadIdx.x & 31, ty = threadIdx.x >> 5;
#pragma unroll
    for (int i = 0; i < 4; ++i) {
      float x = src[(size_t)(r0 + ty + i * 8) * C + c0 + tx];
      bf16_t h, l; split2(x, h, l);
      th[ty + i * 8][tx] = h;
      tl[ty + i * 8][tx] = l;
    }
    __syncthreads();
#pragma unroll
    for (int i = 0; i < 4; ++i) {
      hiT[(size_t)(oc + ty + i * 8) * HDIM + r0 + tx] = th[tx][ty + i * 8];
      loT[(size_t)(oc + ty + i * 8) * HDIM + r0 + tx] = tl[tx][ty + i * 8];
    }
  }
}

// ---------------------------------------------------------------------------
// Shared helpers for pipelined GEMMs
// ---------------------------------------------------------------------------
#define VMCNT_(n) asm volatile("s_waitcnt vmcnt(" #n ")" ::: "memory")
#define VMCNT(n) VMCNT_(n)
#define BARRIER()                     \
  {                                   \
    asm volatile("" ::: "memory");    \
    __builtin_amdgcn_s_barrier();     \
    asm volatile("" ::: "memory");    \
  }

#define MFMA_(a, b, c) __builtin_amdgcn_mfma_f32_16x16x32_bf16(a, b, c, 0, 0, 0)

// ---------------------------------------------------------------------------
// Split-precision GEMM v5 (verified rounds 9/10: 117.5 us, MfmaUtil 59%).
// C = Ah*Bh + Ah*Bl + Al*Bh, pipelined. BM=256, BN=192, BK=32, 768 threads
// (12 waves = 3 waves/SIMD), wave tile 64x64 (acc 4x4 in AGPR). Staging on
// waves 0-7; waves 8-11 compute only. Double-buffered LDS (112 KB), ONE
// barrier + one vmcnt(0) per K-step. XCD-chunked swizzle.
// NOTE: 16-wave/64x48 variant (round 11) REGRESSED to 141 us — smaller
// per-wave tiles raise total LDS fragment traffic (224 vs 192 KB/step);
// LDS BW is the binding resource, not occupancy. Keep 12-wave/64x64.
// ---------------------------------------------------------------------------
#define OFF_AH 0
#define OFF_AL 16384
#define OFF_BH 32768
#define OFF_BL 45056
#define BUFSZ  57344

#define SPLIT_STEP()                                                    \
  {                                                                     \
    fragAB bh[4], bl[4];                                                \
    _Pragma("unroll") for (int j = 0; j < 4; ++j) {                     \
      const char* bp = bufc + (wn + j * 16 + l16) * 64 + rdq;           \
      bh[j] = *(const fragAB*)(bp + OFF_BH);                            \
      bl[j] = *(const fragAB*)(bp + OFF_BL);                            \
    }                                                                   \
    _Pragma("unroll") for (int p = 0; p < 2; ++p) {                     \
      fragAB ah[2], al[2];                                              \
      _Pragma("unroll") for (int u = 0; u < 2; ++u) {                   \
        const char* ap = bufc + (wm + (2 * p + u) * 16 + l16) * 64 + rdq;\
        ah[u] = *(const fragAB*)(ap + OFF_AH);                          \
        al[u] = *(const fragAB*)(ap + OFF_AL);                          \
      }                                                                 \
      __builtin_amdgcn_s_setprio(1);                                    \
      _Pragma("unroll") for (int j = 0; j < 4; ++j)                     \
        _Pragma("unroll") for (int u = 0; u < 2; ++u)                   \
          acc[2 * p + u][j] = MFMA_(al[u], bh[j], acc[2 * p + u][j]);   \
      _Pragma("unroll") for (int j = 0; j < 4; ++j)                     \
        _Pragma("unroll") for (int u = 0; u < 2; ++u)                   \
          acc[2 * p + u][j] = MFMA_(ah[u], bl[j], acc[2 * p + u][j]);   \
      _Pragma("unroll") for (int j = 0; j < 4; ++j)                     \
        _Pragma("unroll") for (int u = 0; u < 2; ++u)                   \
          acc[2 * p + u][j] = MFMA_(ah[u], bh[j], acc[2 * p + u][j]);   \
      __builtin_amdgcn_s_setprio(0);                                    \
    }                                                                   \
  }

__global__ __launch_bounds__(768, 3) void gemm_split2(
    const bf16_t* __restrict__ Ah, const bf16_t* __restrict__ Al,
    const bf16_t* __restrict__ Bh, const bf16_t* __restrict__ Bl,
    float* __restrict__ C, int M, int N, int K) {
  __shared__ __align__(16) char lds[2 * BUFSZ];
  const int t = threadIdx.x;
  const int wave = t >> 6, lane = t & 63;
  const int quad = lane >> 4, l16 = lane & 15;
  // XCD-chunked swizzle (grid 16x16 = 256 = 32/XCD): bijective relabel.
  const int g = blockIdx.y * 16 + blockIdx.x;
  const int lby = (g & 7) * 2 + ((g >> 3) >> 4);
  const int lbx = (g >> 3) & 15;
  const int m0 = lby * 256, n0 = lbx * 192;
  const int wm = (wave / 3) * 64, wn = (wave % 3) * 64;
  // T2 read swizzle: phys 16B-slot of (row r, col-16B q) = q ^ ((r>>1)&3).
  const int rdq = (quad ^ ((l16 >> 1) & 3)) * 16;

  // Per-lane global source offset inside a 16-row x 32-col chunk (inverse swizzle).
  const size_t laneOff =
      (size_t)(lane >> 2) * K * 2 + 16 * ((lane & 3) ^ ((lane >> 3) & 3));

  // 7 staging chunks per wave (waves 0-7 only), identical to 8-wave template.
  const char* gbase[7];
  int ldsOff[7];
  if (wave < 8) {
#pragma unroll
    for (int pos = 0; pos < 3; ++pos) {
      int c = wave + 8 * pos;          // 0..23: Bh chunks 0..11, Bl chunks 0..11
      if (c < 12) {
        gbase[pos]  = (const char*)Bh + (size_t)(n0 + 16 * c) * K * 2;
        ldsOff[pos] = OFF_BH + c * 1024;
      } else {
        gbase[pos]  = (const char*)Bl + (size_t)(n0 + 16 * (c - 12)) * K * 2;
        ldsOff[pos] = OFF_BL + (c - 12) * 1024;
      }
    }
#pragma unroll
    for (int p = 0; p < 4; ++p) {
      int sub = wave & 3;
      int R0 = ((sub >> 1) & 1) * 128 + 32 * p + (sub & 1) * 16;
      const char* base = (const char*)(wave < 4 ? Ah : Al);
      gbase[3 + p]  = base + (size_t)(m0 + R0) * K * 2;
      ldsOff[3 + p] = (wave < 4 ? OFF_AH : OFF_AL) + R0 * 64;
    }
  }

  fragC zero4 = {0.f, 0.f, 0.f, 0.f};
  fragC acc[4][4];
#pragma unroll
  for (int i = 0; i < 4; ++i)
#pragma unroll
    for (int j = 0; j < 4; ++j) acc[i][j] = zero4;

  char* ldsc = (char*)lds;
  // prologue: stage K-step 0 into buffer 0
  if (wave < 8) {
#pragma unroll
    for (int ps = 0; ps < 7; ++ps)
      async_copy16(gbase[ps] + laneOff, ldsc + ldsOff[ps]);
  }

  size_t kk = 64;  // byte offset of next K-step (32 bf16 = 64 B)
  int cur = 0;
  const int NS = K / 32;
  for (int it = 0; it < NS - 1; ++it) {
    const char* bufc = ldsc + cur * BUFSZ;
    char* nb = ldsc + (cur ^ 1) * BUFSZ;
    // drain own loads (issued a full K-step ago -> free) and rendezvous;
    // after the barrier, nb is safe to overwrite.
    VMCNT(0); BARRIER();
    if (wave < 8) {
#pragma unroll
      for (int ps = 0; ps < 7; ++ps)
        async_copy16(gbase[ps] + kk + laneOff, nb + ldsOff[ps]);
    }
    kk += 64;
    SPLIT_STEP();
    cur ^= 1;
  }
  {  // final K-step
    const char* bufc = ldsc + cur * BUFSZ;
    VMCNT(0); BARRIER();
    SPLIT_STEP();
  }

#pragma unroll
  for (int i = 0; i < 4; ++i)
#pragma unroll
    for (int j = 0; j < 4; ++j)
#pragma unroll
      for (int r = 0; r < 4; ++r) {
        int row = m0 + wm + i * 16 + quad * 4 + r;
        int col = n0 + wn + j * 16 + l16;
        C[(size_t)row * N + col] = acc[i][j][r];
      }
}

// ---------------------------------------------------------------------------
// Plain GEMM v4 (output projection): C[M][N] = A[M][K]*Bt[N][K]^T, fp32 out.
// BM=256, BN=128, BK=64, 1024 threads (16 waves = 4 waves/SIMD), wave tile
// 64x32 (4M x 4N, acc 4x2). Staging: 48 chunks = 3/wave. 1-barrier +
// vmcnt(0) per K-step; per-element MFMA k-order unchanged. XCD swizzle.
// (Kept at 16-wave: round-11 delta accounting suggests this variant gained
// ~6 us vs the 8-wave version while split2 16-wave lost 20.)
// ---------------------------------------------------------------------------
#define BT_OFF_A 0
#define BT_OFF_B 32768
#define BT_BUFSZ 49152

#define BT_STEP()                                                         \
  {                                                                       \
    fragAB bfr[2][2];                                                     \
    _Pragma("unroll") for (int j = 0; j < 2; ++j)                         \
      _Pragma("unroll") for (int ks = 0; ks < 2; ++ks)                    \
        bfr[j][ks] = *(const fragAB*)(bufc + BT_OFF_B +                   \
                                      (wn + j * 16 + l16) * 128 +         \
                                      (((ks * 4 + quad) ^ rx) * 16));     \
    _Pragma("unroll") for (int p = 0; p < 2; ++p) {                       \
      fragAB af[2][2];                                                    \
      _Pragma("unroll") for (int u = 0; u < 2; ++u)                       \
        _Pragma("unroll") for (int ks = 0; ks < 2; ++ks)                  \
          af[u][ks] = *(const fragAB*)(bufc + BT_OFF_A +                  \
                                       (wm + (2 * p + u) * 16 + l16) * 128 + \
                                       (((ks * 4 + quad) ^ rx) * 16));    \
      __builtin_amdgcn_s_setprio(1);                                      \
      _Pragma("unroll") for (int ks = 0; ks < 2; ++ks)                    \
        _Pragma("unroll") for (int j = 0; j < 2; ++j)                     \
          _Pragma("unroll") for (int u = 0; u < 2; ++u)                   \
            acc[2 * p + u][j] = MFMA_(af[u][ks], bfr[j][ks], acc[2 * p + u][j]); \
      __builtin_amdgcn_s_setprio(0);                                      \
    }                                                                     \
  }

__global__ __launch_bounds__(1024, 4) void gemm_bt2(
    const bf16_t* __restrict__ A, const bf16_t* __restrict__ Bt,
    float* __restrict__ C, int M, int N, int K) {
  __shared__ __align__(16) char lds[2 * BT_BUFSZ];
  const int t = threadIdx.x;
  const int wave = t >> 6, lane = t & 63;
  const int quad = lane >> 4, l16 = lane & 15;
  const int g = blockIdx.y * 16 + blockIdx.x;
  const int lby = (g & 7) * 2 + ((g >> 3) >> 4);
  const int lbx = (g >> 3) & 15;
  const int m0 = lby * 256, n0 = lbx * 128;
  const int wm = (wave >> 2) * 64, wn = (wave & 3) * 32;
  const int rx = l16 & 7;  // row-XOR for 8-slot swizzle (128B rows)

  // chunk = 8 rows x 64 cols (128B rows). lane l stages row l>>3,
  // logical col16 (l&7)^((l>>3)&7) -> LDS phys slot l&7 (inverse swizzle).
  const size_t laneOff =
      (size_t)(lane >> 3) * K * 2 + 16 * ((lane & 7) ^ ((lane >> 3) & 7));

  // 48 staging chunks: wave w takes c = w+16*pos (pos<3).
  //  c<16: B chunk c (rows 8c) ; c>=16: A chunk c-16 (rows 8(c-16))
  const char* gbase[3];
  int ldsOff[3];
#pragma unroll
  for (int pos = 0; pos < 3; ++pos) {
    int c = wave + 16 * pos;
    if (c < 16) {
      gbase[pos]  = (const char*)Bt + (size_t)(n0 + 8 * c) * K * 2;
      ldsOff[pos] = BT_OFF_B + c * 1024;
    } else {
      gbase[pos]  = (const char*)A + (size_t)(m0 + 8 * (c - 16)) * K * 2;
      ldsOff[pos] = BT_OFF_A + (c - 16) * 1024;
    }
  }

  fragC zero4 = {0.f, 0.f, 0.f, 0.f};
  fragC acc[4][2];
#pragma unroll
  for (int i = 0; i < 4; ++i)
#pragma unroll
    for (int j = 0; j < 2; ++j) acc[i][j] = zero4;

  char* ldsc = (char*)lds;
#pragma unroll
  for (int ps = 0; ps < 3; ++ps)
    async_copy16(gbase[ps] + laneOff, ldsc + ldsOff[ps]);

  size_t kk = 128;  // byte offset of next K-step (64 bf16 = 128 B)
  int cur = 0;
  const int NS = K / 64;
  for (int it = 0; it < NS - 1; ++it) {
    const char* bufc = ldsc + cur * BT_BUFSZ;
    char* nb = ldsc + (cur ^ 1) * BT_BUFSZ;
    VMCNT(0); BARRIER();
#pragma unroll
    for (int ps = 0; ps < 3; ++ps)
      async_copy16(gbase[ps] + kk + laneOff, nb + ldsOff[ps]);
    kk += 128;
    BT_STEP();
    cur ^= 1;
  }
  {
    const char* bufc = ldsc + cur * BT_BUFSZ;
    VMCNT(0); BARRIER();
    BT_STEP();
  }

#pragma unroll
  for (int i = 0; i < 4; ++i)
#pragma unroll
    for (int j = 0; j < 2; ++j)
#pragma unroll
      for (int r = 0; r < 4; ++r) {
        int row = m0 + wm + i * 16 + quad * 4 + r;
        int col = n0 + wn + j * 16 + l16;
        C[(size_t)row * N + col] = acc[i][j][r];
      }
}

// ---------------------------------------------------------------------------
// prep2: fused phase-2 norms + w_o transpose (one dispatch).
//  bx <  10240         : RMS-norm+RoPE q/k, wave-per-(s,head), split output
//  10240 <= bx < 10496 : RMS-norm v + transposed write [NKV][D][S]
//  bx >= 10496         : transpose+convert w_o -> woT  (woT ALIASES wTl;
//                        this kernel runs AFTER gemm_split2 -- lifetime OK)
// ---------------------------------------------------------------------------
__global__ __launch_bounds__(256) void prep2(
    const float* __restrict__ proj, const float* __restrict__ qnw,
    const float* __restrict__ knw, const float* __restrict__ cosb,
    const float* __restrict__ sinb, bf16_t* __restrict__ qhi,
    bf16_t* __restrict__ qlo, bf16_t* __restrict__ khi,
    bf16_t* __restrict__ klo, bf16_t* __restrict__ vt,
    const float* __restrict__ wo, bf16_t* __restrict__ woT) {
  __shared__ float rs_[32];
  __shared__ bf16_t tile[32][33];
  int bx = blockIdx.x;
  if (bx < 10240) {
    // ---- RMS-norm + RoPE for q/k heads (wave-per-(s,head)) ----
    const int wv = threadIdx.x >> 6, lane = threadIdx.x & 63;
    const int idx = bx * 4 + wv;
    const int s = idx / (NHQ + NKVH), hb = idx % (NHQ + NKVH);
    const float* w; bf16_t* oh; bf16_t* ol; int inOff, outStride, oBase;
    if (hb < NHQ) {
      w = qnw; oh = qhi; ol = qlo;
      inOff = hb * DHEAD; outStride = NHQ * DHEAD; oBase = hb * DHEAD;
    } else {
      int hk = hb - NHQ;
      w = knw; oh = khi; ol = klo;
      inOff = NHQ * DHEAD + hk * DHEAD; outStride = NKVH * DHEAD; oBase = hk * DHEAD;
    }
    const int d = lane * 4;
    float4 x = *(const float4*)(proj + (size_t)s * NQKV + inOff + d);
    float ss = x.x * x.x + x.y * x.y + x.z * x.z + x.w * x.w;
    ss += __shfl_xor(ss, 1);  ss += __shfl_xor(ss, 2);  ss += __shfl_xor(ss, 4);
    ss += __shfl_xor(ss, 8);  ss += __shfl_xor(ss, 16); ss += __shfl_xor(ss, 32);
    float r = rsqrtf(ss * (1.0f / DHEAD) + 1e-6f);
    float4 w4 = *(const float4*)(w + d);
    float xn[4] = {x.x * r * w4.x, x.y * r * w4.y, x.z * r * w4.z, x.w * r * w4.w};
    float ot[4];
#pragma unroll
    for (int j = 0; j < 4; ++j) ot[j] = __shfl_xor(xn[j], 32);
    float sgn = (lane < 32) ? -1.0f : 1.0f;
    float4 c4 = *(const float4*)(cosb + (size_t)s * DHEAD + d);
    float4 s4 = *(const float4*)(sinb + (size_t)s * DHEAD + d);
    float cc[4] = {c4.x, c4.y, c4.z, c4.w};
    float sn[4] = {s4.x, s4.y, s4.z, s4.w};
    bf16x4 hv, lv;
#pragma unroll
    for (int j = 0; j < 4; ++j) {
      float y = xn[j] * cc[j] + sgn * ot[j] * sn[j];
      split2(y, hv.v[j], lv.v[j]);
    }
    size_t o = (size_t)s * outStride + oBase + d;
    *(bf16x4*)(oh + o) = hv;
    *(bf16x4*)(ol + o) = lv;
  } else if (bx < 10240 + 256) {
    // ---- RMS-norm v (no weight) + transposed write [NKV][D][S] ----
    int b2 = bx - 10240;
    int s0 = (b2 & 127) * 32, hh = b2 >> 7;
    const int inOff = NHQ * DHEAD + NKVH * DHEAD;
    const float* base = proj + (size_t)s0 * NQKV + inOff + hh * DHEAD;
    int t = threadIdx.x;
    int sl = t >> 3, c8 = t & 7;
    const float4* rowp = (const float4*)(base + (size_t)sl * NQKV + c8 * 32);
    float ss = 0.f;
#pragma unroll
    for (int i = 0; i < 8; ++i) {
      float4 v = rowp[i];
      ss += v.x * v.x + v.y * v.y + v.z * v.z + v.w * v.w;
    }
    ss += __shfl_xor(ss, 1); ss += __shfl_xor(ss, 2); ss += __shfl_xor(ss, 4);
    if (c8 == 0) rs_[sl] = rsqrtf(ss * (1.0f / DHEAD) + 1e-6f);
    __syncthreads();
    int tx = t & 31, ty = t >> 5;
#pragma unroll
    for (int ch = 0; ch < 8; ++ch) {
#pragma unroll
      for (int i = 0; i < 4; ++i) {
        int s_ = ty + i * 8;
        float x = base[(size_t)s_ * NQKV + ch * 32 + tx];
        tile[s_][tx] = __float2bfloat16(x * rs_[s_]);
      }
      __syncthreads();
#pragma unroll
      for (int i = 0; i < 4; ++i) {
        int dl = ty + i * 8;
        vt[((size_t)hh * DHEAD + ch * 32 + dl) * S_LEN + s0 + tx] = tile[tx][dl];
      }
      __syncthreads();
    }
  } else {
    // ---- transpose+convert w_o [2048][2048] -> woT ----
    int b2 = bx - 10496;
    int c0 = (b2 & 63) * 32, r0 = (b2 >> 6) * 32;
    int tx = threadIdx.x & 31, ty = threadIdx.x >> 5;
#pragma unroll
    for (int i = 0; i < 4; ++i)
      tile[ty + i * 8][tx] =
          __float2bfloat16(wo[(size_t)(r0 + ty + i * 8) * HDIM + c0 + tx]);
    __syncthreads();
#pragma unroll
    for (int i = 0; i < 4; ++i)
      woT[(size_t)(c0 + ty + i * 8) * (NHQ * DHEAD) + r0 + tx] = tile[tx][ty + i * 8];
  }
}

// ---------------------------------------------------------------------------
// Flash attention v4: Q=128, KV=32, dbuf, 1 barrier/step, setprio around
// MFMA clusters, XCD-chunked block swizzle.
// ---------------------------------------------------------------------------
__global__ __launch_bounds__(512, 2) void attn_split(
    const bf16_t* __restrict__ Qhi, const bf16_t* __restrict__ Qlo,
    const bf16_t* __restrict__ Khi, const bf16_t* __restrict__ Klo,
    const bf16_t* __restrict__ Vt, bf16_t* __restrict__ Aout) {
  const int g = blockIdx.y * 32 + blockIdx.x;
  const int lbx = (g & 7) * 4 + ((g >> 3) & 3);
  const int h = g >> 5;
  const int qb = lbx * 128;
  const int wave = threadIdx.x >> 6, lane = threadIdx.x & 63;
  const int quad = lane >> 4, l16 = lane & 15;
  const int qw = qb + wave * 16;
  const int kv = h >> 2;  // G = 4
  const bf16_t* Qh_ = Qhi + h * DHEAD;   // row stride NHQ*DHEAD
  const bf16_t* Ql_ = Qlo + h * DHEAD;
  const bf16_t* Kh_ = Khi + kv * DHEAD;  // row stride NKVH*DHEAD
  const bf16_t* Kl_ = Klo + kv * DHEAD;
  const bf16_t* Vh_ = Vt + (size_t)kv * DHEAD * S_LEN;

  __shared__ __align__(16) bf16_t KshH[2][32 * 256];  // 2x16 KB (keys x d)
  __shared__ __align__(16) bf16_t KshL[2][32 * 256];  // 2x16 KB
  __shared__ __align__(16) bf16_t Vsh[2][256 * 32];   // 2x16 KB (d x keys)
  __shared__ __align__(16) bf16_t Plds[8][16 * 32];   // 8 KB

  fragAB qfh[8], qfl[8];
#pragma unroll
  for (int c = 0; c < 8; ++c) {
    size_t off = (size_t)(qw + l16) * (NHQ * DHEAD) + c * 32 + quad * 8;
    qfh[c] = *(const fragAB*)(Qh_ + off);
    qfl[c] = *(const fragAB*)(Ql_ + off);
  }

  int kRow[2], kCol[2], vRow[2], vCol[2];
#pragma unroll
  for (int i = 0; i < 2; ++i) {
    int ci = i * 512 + threadIdx.x;
    kRow[i] = ci >> 5;
    kCol[i] = ((ci & 31) ^ (kRow[i] & 31)) * 8;
    vRow[i] = ci >> 2;
    vCol[i] = ((ci & 3) ^ (vRow[i] & 3)) * 8;
  }

#define ASTAGE(buf, kb_)                                                     \
  _Pragma("unroll")                                                          \
  for (int i = 0; i < 2; ++i) {                                              \
    size_t dst = (size_t)(i * 512 + threadIdx.x) * 16;                       \
    size_t koff = (size_t)((kb_) + kRow[i]) * (NKVH * DHEAD) + kCol[i];      \
    async_copy16(Kh_ + koff, (char*)KshH[buf] + dst);                        \
    async_copy16(Kl_ + koff, (char*)KshL[buf] + dst);                        \
    async_copy16(Vh_ + (size_t)vRow[i] * S_LEN + (kb_) + vCol[i],            \
                 (char*)Vsh[buf] + dst);                                     \
  }

  fragC zero4 = {0.f, 0.f, 0.f, 0.f};
  fragC o_acc[16];
#pragma unroll
  for (int c = 0; c < 16; ++c) o_acc[c] = zero4;
  float m_run[4] = {NEG_BIG, NEG_BIG, NEG_BIG, NEG_BIG};
  float l_run[4] = {0.f, 0.f, 0.f, 0.f};
  const float LOG2E = 1.4426950408889634f;

  int k_lo = qb - (WIN - 1);
  if (k_lo < 0) k_lo = 0;
  k_lo &= ~31;

  // prologue: stage first KV tile into buffer 0
  ASTAGE(0, k_lo);
  int cur = 0;

  for (int kb = k_lo; kb < qb + 128; kb += 32) {
    VMCNT(0); BARRIER();
    if (kb + 32 < qb + 128) {
      int nbuf = cur ^ 1;
      ASTAGE(nbuf, kb + 32);
    }
    const char* KH = (const char*)KshH[cur];
    const char* KL = (const char*)KshL[cur];
    const char* VB = (const char*)Vsh[cur];

    fragC s[2] = {zero4, zero4};
    __builtin_amdgcn_s_setprio(1);
#pragma unroll
    for (int c = 0; c < 8; ++c) {
      int j = c * 4 + quad;
#pragma unroll
      for (int gg = 0; gg < 2; ++gg) {
        int row = gg * 16 + l16;
        int off = (row * 32 + (j ^ (row & 31))) * 16;
        fragAB kh = *(const fragAB*)(KH + off);
        fragAB kl = *(const fragAB*)(KL + off);
        s[gg] = __builtin_amdgcn_mfma_f32_16x16x32_bf16(qfl[c], kh, s[gg], 0, 0, 0);
        s[gg] = __builtin_amdgcn_mfma_f32_16x16x32_bf16(qfh[c], kl, s[gg], 0, 0, 0);
        s[gg] = __builtin_amdgcn_mfma_f32_16x16x32_bf16(qfh[c], kh, s[gg], 0, 0, 0);
      }
    }
    __builtin_amdgcn_s_setprio(0);

    float p[2][4], alpha[4];
#pragma unroll
    for (int r = 0; r < 4; ++r) {
      int qi = qw + quad * 4 + r;
      bool vld[2];
      float mx = NEG_BIG;
#pragma unroll
      for (int gg = 0; gg < 2; ++gg) {
        int ki = kb + gg * 16 + l16;
        vld[gg] = (ki <= qi) && (qi - ki < WIN);
        mx = fmaxf(mx, vld[gg] ? s[gg][r] : NEG_BIG);
      }
      mx = fmaxf(mx, __shfl_xor(mx, 1));
      mx = fmaxf(mx, __shfl_xor(mx, 2));
      mx = fmaxf(mx, __shfl_xor(mx, 4));
      mx = fmaxf(mx, __shfl_xor(mx, 8));
      float mn = fmaxf(m_run[r], mx);
      float a  = exp2f(fmaxf(m_run[r] - mn, -80.f) * LOG2E);
      float rs = 0.f;
#pragma unroll
      for (int gg = 0; gg < 2; ++gg) {
        float e = vld[gg] ? exp2f(fmaxf(s[gg][r] - mn, -80.f) * LOG2E) : 0.f;
        p[gg][r] = e;
        rs += e;
      }
      rs += __shfl_xor(rs, 1);
      rs += __shfl_xor(rs, 2);
      rs += __shfl_xor(rs, 4);
      rs += __shfl_xor(rs, 8);
      l_run[r] = l_run[r] * a + rs;
      m_run[r] = mn;
      alpha[r] = a;
    }
#pragma unroll
    for (int c = 0; c < 16; ++c)
#pragma unroll
      for (int r = 0; r < 4; ++r) o_acc[c][r] *= alpha[r];

    bf16_t* Pw = Plds[wave];
#pragma unroll
    for (int r = 0; r < 4; ++r)
#pragma unroll
      for (int gg = 0; gg < 2; ++gg)
        Pw[(quad * 4 + r) * 32 + gg * 16 + l16] = __float2bfloat16(p[gg][r]);
    fragAB pf = *(const fragAB*)((const char*)Pw + l16 * 64 + quad * 16);

    __builtin_amdgcn_s_setprio(1);
#pragma unroll
    for (int c = 0; c < 16; ++c) {
      int d = c * 16 + l16;
      int offv = (d * 4 + (quad ^ (d & 3))) * 16;
      fragAB vf = *(const fragAB*)(VB + offv);
      o_acc[c] = __builtin_amdgcn_mfma_f32_16x16x32_bf16(pf, vf, o_acc[c], 0, 0, 0);
    }
    __builtin_amdgcn_s_setprio(0);
    cur ^= 1;
  }

  float inv_l[4];
#pragma unroll
  for (int r = 0; r < 4; ++r) inv_l[r] = 1.0f / l_run[r];
#pragma unroll
  for (int c = 0; c < 16; ++c)
#pragma unroll
    for (int r = 0; r < 4; ++r) {
      int row = qw + quad * 4 + r;
      int col = h * DHEAD + c * 16 + l16;
      Aout[(size_t)row * (NHQ * DHEAD) + col] = __float2bfloat16(o_acc[c][r] * inv_l[r]);
    }
#undef ASTAGE
}

// ---------------------------------------------------------------------------
extern "C" void kernel_launch(void* const* d_in, const int* in_sizes, int n_in,
                              void* d_out, int out_size, void* d_ws, size_t ws_size,
                              hipStream_t stream) {
  const float* hid  = (const float*)d_in[0];
  const float* w_q  = (const float*)d_in[1];
  const float* w_k  = (const float*)d_in[2];
  const float* w_v  = (const float*)d_in[3];
  const float* w_o  = (const float*)d_in[4];
  const float* qnw  = (const float*)d_in[5];
  const float* knw  = (const float*)d_in[6];
  const float* cosb = (const float*)d_in[7];
  const float* sinb = (const float*)d_in[8];
  float* outp = (float*)d_out;

  // Workspace (bf16 slots, M1 = 1<<20), peak 52M slots = 104 MiB:
  //  [ 0: 8M)  hidh  -> qh  (after qkv gemm)
  //  [ 8:16M)  hidl  -> ql
  //  [16:22M)  wTh (3072x2048) -> kh[16:18M), kl[18:20M), vt[20:22M) after gemm
  //  [22:28M)  wTl   -> woT[22:26M) after gemm  (LIFETIME: woT writes must
  //            come AFTER gemm_split2 — rounds 6/7 bug wrote it at phase 0)
  //  [28:52M)  projqkv f32 (4096x3072) -> aout[28:36M) after norms
  const size_t M1 = 1048576;
  bf16_t* w = (bf16_t*)d_ws;
  bf16_t* hidh  = w;
  bf16_t* qh    = w;                         // alias hidh
  bf16_t* hidl  = w + 8 * M1;
  bf16_t* ql    = w + 8 * M1;                // alias hidl
  bf16_t* wTh   = w + 16 * M1;
  bf16_t* kh    = w + 16 * M1;               // alias wTh
  bf16_t* kl    = w + 18 * M1;
  bf16_t* vt    = w + 20 * M1;
  bf16_t* wTl   = w + 22 * M1;
  bf16_t* woT   = w + 22 * M1;               // alias wTl
  float*  projqkv = (float*)(w + 28 * M1);
  bf16_t* aout  = w + 28 * M1;               // alias projqkv (after norms)

  // phase 0: ONE dispatch — split hidden + split-transpose [wq|wk|wv]
  prep0<<<4096 + 96 * 64, 256, 0, stream>>>(
      hid, hidh, hidl, w_q, w_k, w_v, wTh, wTl);

  // phase 1: fused q+k+v split projection, pipelined 256x192 tiles
  //          grid 16x16 = 256 blocks = exactly 1 per CU, 12 waves (3/SIMD)
  gemm_split2<<<dim3(NQKV / 192, S_LEN / 256), 768, 0, stream>>>(
      hidh, hidl, wTh, wTl, projqkv, S_LEN, NQKV, HDIM);

  // phase 2: ONE dispatch — q/k norm+rope, v norm+transpose, w_o transpose
  //          (woT aliases wTl: safe only AFTER gemm_split2)
  prep2<<<10240 + 256 + 4096, 256, 0, stream>>>(
      projqkv, qnw, knw, cosb, sinb, qh, ql, kh, kl, vt, w_o, woT);

  // phase 3: attention -> aout (dead projqkv region)
  //          grid 32x8 = 256 blocks = exactly 1 per CU
  attn_split<<<dim3(S_LEN / 128, NHQ), 512, 0, stream>>>(qh, ql, kh, kl, vt, aout);

  // phase 4: output projection -> fp32 d_out, pipelined 256x128 tiles
  //          grid 16x16 = 256 blocks = 1 per CU, 16 waves (4/SIMD)
  gemm_bt2<<<dim3(HDIM / 128, S_LEN / 256), 1024, 0, stream>>>(
      aout, woT, outp, S_LEN, HDIM, NHQ * DHEAD);
}